// Round 1
// baseline (1868.114 us; speedup 1.0000x reference)
//
#include <hip/hip_runtime.h>
#include <cmath>

#define NUs 32768
#define NIs 8192
#define NNs 40960   // NUs + NIs
#define NEs 2000000

__device__ __forceinline__ float4 ld4(const float* p){ return *reinterpret_cast<const float4*>(p); }
__device__ __forceinline__ void st4(float* p, float4 v){ *reinterpret_cast<float4*>(p) = v; }

// ---------------- CSR build ----------------
__global__ void k_hist(const int* __restrict__ eu, const int* __restrict__ ev, int* __restrict__ cnt){
    int e = blockIdx.x*blockDim.x + threadIdx.x;
    if (e < NEs){ atomicAdd(&cnt[eu[e]], 1); atomicAdd(&cnt[ev[e]], 1); }
}

__global__ void k_bsum(const int* __restrict__ cnt, int* __restrict__ bsum){
    __shared__ int s[256];
    int i = blockIdx.x*256 + threadIdx.x;
    s[threadIdx.x] = cnt[i];
    __syncthreads();
    for (int off=128; off>0; off>>=1){
        if (threadIdx.x < off) s[threadIdx.x] += s[threadIdx.x+off];
        __syncthreads();
    }
    if (threadIdx.x == 0) bsum[blockIdx.x] = s[0];
}

__global__ void k_bscan(const int* __restrict__ bsum, int* __restrict__ boff){
    __shared__ int s[256];
    int t = threadIdx.x;
    int v0 = (t < 160) ? bsum[t] : 0;
    s[t] = v0;
    __syncthreads();
    for (int off=1; off<256; off<<=1){
        int v = (t >= off) ? s[t-off] : 0;
        __syncthreads();
        s[t] += v;
        __syncthreads();
    }
    if (t < 160) boff[t] = s[t] - v0;   // exclusive block offsets
}

__global__ void k_ptr(const int* __restrict__ cnt, const int* __restrict__ boff,
                      int* __restrict__ ptr, int* __restrict__ fill){
    __shared__ int s[256];
    int t = threadIdx.x; int i = blockIdx.x*256 + t;
    int c = cnt[i];
    s[t] = c; __syncthreads();
    for (int off=1; off<256; off<<=1){
        int v = (t >= off) ? s[t-off] : 0;
        __syncthreads();
        s[t] += v;
        __syncthreads();
    }
    int excl = boff[blockIdx.x] + s[t] - c;
    ptr[i] = excl; fill[i] = excl;
    if (i == NNs-1) ptr[NNs] = excl + c;
}

__global__ void k_scatter(const int* __restrict__ eu, const int* __restrict__ ev,
                          int* __restrict__ fill, int* __restrict__ csrc, int* __restrict__ ceid){
    int e = blockIdx.x*blockDim.x + threadIdx.x;
    if (e >= NEs) return;
    int u = eu[e], v = ev[e];
    int p = atomicAdd(&fill[v], 1); csrc[p] = u; ceid[p] = e;   // dst = item
    int q = atomicAdd(&fill[u], 1); csrc[q] = v; ceid[q] = e;   // dst = user
}

// ---------------- feature GEMMs: out(NI x 64) = A(NI x K) @ W(64 x K)^T + bias ----------------
template<int K>
__global__ __launch_bounds__(256) void k_featgemm(const float* __restrict__ A, const float* __restrict__ W,
                                                  const float* __restrict__ bias, float* __restrict__ out){
    __shared__ float As[64][65];
    __shared__ float Ws[64][65];
    int tid = threadIdx.x;
    int tx = tid & 15, ty = tid >> 4;
    int r0 = blockIdx.x * 64;
    float acc[4][4] = {};
    for (int kt = 0; kt < K; kt += 64){
        #pragma unroll
        for (int l = 0; l < 16; l++){
            int i = l*256 + tid;
            int rr = i >> 6, kk = i & 63;
            As[rr][kk] = A[(size_t)(r0+rr)*K + kt + kk];
            Ws[rr][kk] = W[(size_t)rr*K + kt + kk];
        }
        __syncthreads();
        #pragma unroll 8
        for (int kk = 0; kk < 64; kk++){
            float a[4], b[4];
            #pragma unroll
            for (int i = 0; i < 4; i++){ a[i] = As[ty*4+i][kk]; b[i] = Ws[tx*4+i][kk]; }
            #pragma unroll
            for (int i = 0; i < 4; i++)
                #pragma unroll
                for (int j = 0; j < 4; j++)
                    acc[i][j] += a[i]*b[j];
        }
        __syncthreads();
    }
    #pragma unroll
    for (int i = 0; i < 4; i++)
        #pragma unroll
        for (int j = 0; j < 4; j++)
            out[(size_t)(r0+ty*4+i)*64 + tx*4+j] = acc[i][j] + bias[tx*4+j];
}

// ---------------- KNN SpMM + l2norm (rows are repeat(arange, 10)) ----------------
__global__ __launch_bounds__(256) void k_spmm_l2(const int* __restrict__ idx, const float* __restrict__ vals,
                                                 const float* __restrict__ src, float* __restrict__ out,
                                                 int stride, int parts){
    int wave = (blockIdx.x*blockDim.x + threadIdx.x) >> 6;
    if (wave >= NIs) return;
    int lane = threadIdx.x & 63;
    const int* cols = idx + stride;
    float acc = 0.f;
    for (int part = 0; part < parts; part++){
        int base = part*81920 + wave*10;
        #pragma unroll
        for (int j = 0; j < 10; j++){
            int e = base + j;
            acc += vals[e] * src[(size_t)cols[e]*64 + lane];
        }
    }
    float ss = acc*acc;
    #pragma unroll
    for (int mset = 1; mset < 64; mset <<= 1) ss += __shfl_xor(ss, mset, 64);
    float nrm = fmaxf(sqrtf(ss), 1e-12f);
    out[(size_t)wave*64 + lane] = acc / nrm;
}

// ---------------- propagate init: ego = accm = concat(user_emb, item_part) ----------------
__global__ __launch_bounds__(256) void k_init(const float* __restrict__ ue, const float* __restrict__ it,
                                              float* __restrict__ ego, float* __restrict__ accm){
    int i = blockIdx.x*blockDim.x + threadIdx.x;
    if (i >= NNs*16) return;
    int n = i >> 4, c = i & 15;
    float4 v = (n < NUs) ? ld4(ue + (size_t)n*64 + c*4)
                         : ld4(it + (size_t)(n-NUs)*64 + c*4);
    st4(ego  + (size_t)n*64 + c*4, v);
    st4(accm + (size_t)n*64 + c*4, v);
}

// ---------------- mask pass (user side): m[e] = (ego[u].ego[i] >= 0), user dinv ----------------
__global__ __launch_bounds__(256) void k_mask(const int* __restrict__ ptr, const int* __restrict__ csrc,
                                              const int* __restrict__ ceid, const float* __restrict__ ego,
                                              float* __restrict__ mbuf, float* __restrict__ dinv){
    int wave = (blockIdx.x*blockDim.x + threadIdx.x) >> 6;
    if (wave >= NUs) return;
    int lane = threadIdx.x & 63;
    int q = lane >> 4, r = lane & 15;
    float4 eu4 = ld4(ego + (size_t)wave*64 + r*4);
    int jb = ptr[wave], je = ptr[wave+1];
    float msum = 0.f;
    for (int j = jb + q; j < je; j += 4){
        int s = csrc[j]; int eid = ceid[j];
        float4 v = ld4(ego + (size_t)s*64 + r*4);
        float d = eu4.x*v.x + eu4.y*v.y + eu4.z*v.z + eu4.w*v.w;
        d += __shfl_xor(d, 1, 64);
        d += __shfl_xor(d, 2, 64);
        d += __shfl_xor(d, 4, 64);
        d += __shfl_xor(d, 8, 64);
        float mv = (d >= 0.f) ? 1.f : 0.f;
        if (r == 0){ mbuf[eid] = mv; msum += mv; }
    }
    msum += __shfl_xor(msum, 16, 64);
    msum += __shfl_xor(msum, 32, 64);
    if (lane == 0) dinv[wave] = rsqrtf(msum + 1.0f);
}

// ---------------- item-side masked degree ----------------
__global__ __launch_bounds__(256) void k_itemdeg(const int* __restrict__ ptr, const int* __restrict__ ceid,
                                                 const float* __restrict__ mbuf, float* __restrict__ dinv){
    int wave = (blockIdx.x*blockDim.x + threadIdx.x) >> 6;
    if (wave >= NIs) return;
    int n = NUs + wave;
    int lane = threadIdx.x & 63;
    int jb = ptr[n], je = ptr[n+1];
    float s = 0.f;
    for (int j = jb + lane; j < je; j += 64) s += mbuf[ceid[j]];
    #pragma unroll
    for (int k = 1; k < 64; k <<= 1) s += __shfl_xor(s, k, 64);
    if (lane == 0) dinv[n] = rsqrtf(s + 1.0f);
}

// ---------------- unmasked dinv from counts ----------------
__global__ void k_dinvcnt(const int* __restrict__ ptr, float* __restrict__ dinv){
    int n = blockIdx.x*blockDim.x + threadIdx.x;
    if (n < NNs) dinv[n] = rsqrtf((float)(ptr[n+1]-ptr[n]) + 1.0f);
}

// ---------------- per-layer 64x64 GEMM with dinv premultiply: g = (ego @ W^T) * dinv[row] ----------------
__global__ __launch_bounds__(256) void k_gemm64(const float* __restrict__ ego, const float* __restrict__ W,
                                                const float* __restrict__ dinv, float* __restrict__ g){
    __shared__ float WT[64*65];
    int tid = threadIdx.x;
    #pragma unroll
    for (int l = 0; l < 16; l++){
        int i = l*256 + tid;
        int d = i >> 6, k = i & 63;
        WT[k*65 + d] = W[i];
    }
    __syncthreads();
    int lane = tid & 63; int wv = tid >> 6;
    int row = blockIdx.x*4 + wv;
    const float* er = ego + (size_t)row*64;
    float acc = 0.f;
    #pragma unroll 8
    for (int k = 0; k < 64; k++) acc += er[k] * WT[k*65 + lane];
    g[(size_t)row*64 + lane] = acc * dinv[row];
}

// ---------------- aggregation: ego' = dinv_dst*(sum_{src,m=1} g[src] + g[dst]) + b; accm += ego' ----------------
template<bool MASKED>
__global__ __launch_bounds__(256) void k_agg(const int* __restrict__ ptr, const int* __restrict__ csrc,
                                             const int* __restrict__ ceid, const float* __restrict__ mbuf,
                                             const float* __restrict__ g, const float* __restrict__ dinv,
                                             const float* __restrict__ bias,
                                             float* __restrict__ egon, float* __restrict__ accm){
    int wave = (blockIdx.x*blockDim.x + threadIdx.x) >> 6;
    if (wave >= NNs) return;
    int lane = threadIdx.x & 63;
    int q = lane >> 4, r = lane & 15;
    int jb = ptr[wave], je = ptr[wave+1];
    float4 acc = {0.f,0.f,0.f,0.f};
    int j = jb + q;
    for (; j + 4 < je; j += 8){
        int s0 = csrc[j], s1 = csrc[j+4];
        float w0 = 1.f, w1 = 1.f;
        if (MASKED){ w0 = mbuf[ceid[j]]; w1 = mbuf[ceid[j+4]]; }
        if (!MASKED || w0 != 0.f){
            float4 v = ld4(g + (size_t)s0*64 + r*4);
            acc.x += v.x; acc.y += v.y; acc.z += v.z; acc.w += v.w;
        }
        if (!MASKED || w1 != 0.f){
            float4 v = ld4(g + (size_t)s1*64 + r*4);
            acc.x += v.x; acc.y += v.y; acc.z += v.z; acc.w += v.w;
        }
    }
    if (j < je){
        float w0 = 1.f;
        if (MASKED) w0 = mbuf[ceid[j]];
        if (!MASKED || w0 != 0.f){
            float4 v = ld4(g + (size_t)csrc[j]*64 + r*4);
            acc.x += v.x; acc.y += v.y; acc.z += v.z; acc.w += v.w;
        }
    }
    // reduce across the 4 q-groups
    acc.x += __shfl_xor(acc.x, 16, 64); acc.y += __shfl_xor(acc.y, 16, 64);
    acc.z += __shfl_xor(acc.z, 16, 64); acc.w += __shfl_xor(acc.w, 16, 64);
    acc.x += __shfl_xor(acc.x, 32, 64); acc.y += __shfl_xor(acc.y, 32, 64);
    acc.z += __shfl_xor(acc.z, 32, 64); acc.w += __shfl_xor(acc.w, 32, 64);
    if (q == 0){
        float dn = dinv[wave];
        float4 gs = ld4(g + (size_t)wave*64 + r*4);
        float4 o;
        o.x = dn*(acc.x + gs.x) + bias[r*4+0];
        o.y = dn*(acc.y + gs.y) + bias[r*4+1];
        o.z = dn*(acc.z + gs.z) + bias[r*4+2];
        o.w = dn*(acc.w + gs.w) + bias[r*4+3];
        st4(egon + (size_t)wave*64 + r*4, o);
        float4 am = ld4(accm + (size_t)wave*64 + r*4);
        am.x += o.x; am.y += o.y; am.z += o.z; am.w += o.w;
        st4(accm + (size_t)wave*64 + r*4, am);
    }
}

// ---------------- final: out[:, p*64:(p+1)*64] = accm/3 (+ extra for item rows) ----------------
__global__ __launch_bounds__(256) void k_final(const float* __restrict__ accm, const float* __restrict__ extra,
                                               float* __restrict__ out, int p){
    int i = blockIdx.x*blockDim.x + threadIdx.x;
    if (i >= NNs*16) return;
    int n = i >> 4, c = i & 15;
    float4 v = ld4(accm + (size_t)n*64 + c*4);
    const float third = 1.0f/3.0f;
    v.x *= third; v.y *= third; v.z *= third; v.w *= third;
    if (n >= NUs){
        float4 e = ld4(extra + (size_t)(n-NUs)*64 + c*4);
        v.x += e.x; v.y += e.y; v.z += e.z; v.w += e.w;
    }
    st4(out + (size_t)n*192 + p*64 + c*4, v);
}

extern "C" void kernel_launch(void* const* d_in, const int* in_sizes, int n_in,
                              void* d_out, int out_size, void* d_ws, size_t ws_size,
                              hipStream_t stream){
    const float* user_emb = (const float*)d_in[0];
    const float* item_emb = (const float*)d_in[1];
    const float* v_feat   = (const float*)d_in[2];
    const float* t_feat   = (const float*)d_in[3];
    const float* Wi       = (const float*)d_in[4];
    const float* bi       = (const float*)d_in[5];
    const float* Wt       = (const float*)d_in[6];
    const float* bt       = (const float*)d_in[7];
    const float* convW    = (const float*)d_in[8];
    const float* convb    = (const float*)d_in[9];
    const int*   edge     = (const int*)d_in[10];
    const int*   img_idx  = (const int*)d_in[11];
    const float* img_vals = (const float*)d_in[12];
    const int*   txt_idx  = (const int*)d_in[13];
    const float* txt_vals = (const float*)d_in[14];
    const int*   mm_idx   = (const int*)d_in[15];
    const float* mm_vals  = (const float*)d_in[16];
    float* out = (float*)d_out;

    const int* eu = edge;
    const int* ev = edge + NEs;

    char* wsb = (char*)d_ws;
    size_t off = 0;
    auto alloc = [&](size_t b)->char*{ char* p = wsb + off; off = (off + b + 255) & ~(size_t)255; return p; };
    int*   cnt   = (int*)  alloc((size_t)NNs*4);
    int*   fill  = (int*)  alloc((size_t)NNs*4);
    int*   ptr   = (int*)  alloc((size_t)(NNs+1)*4);
    int*   bsum  = (int*)  alloc(160*4);
    int*   boff  = (int*)  alloc(160*4);
    int*   csrc  = (int*)  alloc((size_t)2*NEs*4);
    int*   ceid  = (int*)  alloc((size_t)2*NEs*4);
    float* mbuf  = (float*)alloc((size_t)NEs*4);
    float* dinv  = (float*)alloc((size_t)NNs*4);
    float* ego_a = (float*)alloc((size_t)NNs*64*4);
    float* ego_b = (float*)alloc((size_t)NNs*64*4);
    float* gbuf  = (float*)alloc((size_t)NNs*64*4);
    float* accm  = (float*)alloc((size_t)NNs*64*4);
    float* vemb  = (float*)alloc((size_t)NIs*64*4);
    float* temb  = (float*)alloc((size_t)NIs*64*4);
    float* hbuf  = (float*)alloc((size_t)NIs*64*4);
    float* h1buf = (float*)alloc((size_t)NIs*64*4);
    float* h2buf = (float*)alloc((size_t)NIs*64*4);

    // ---- CSR build ----
    hipMemsetAsync(cnt, 0, (size_t)NNs*4, stream);
    int eblk = (NEs + 255)/256;
    k_hist<<<eblk, 256, 0, stream>>>(eu, ev, cnt);
    k_bsum<<<160, 256, 0, stream>>>(cnt, bsum);
    k_bscan<<<1, 256, 0, stream>>>(bsum, boff);
    k_ptr<<<160, 256, 0, stream>>>(cnt, boff, ptr, fill);
    k_scatter<<<eblk, 256, 0, stream>>>(eu, ev, fill, csrc, ceid);

    // ---- feature embeddings ----
    k_featgemm<1024><<<128, 256, 0, stream>>>(v_feat, Wi, bi, vemb);
    k_featgemm<384> <<<128, 256, 0, stream>>>(t_feat, Wt, bt, temb);

    // ---- KNN spmm + l2norm ----
    k_spmm_l2<<<2048, 256, 0, stream>>>(mm_idx,  mm_vals,  item_emb, hbuf,  163840, 2);
    k_spmm_l2<<<2048, 256, 0, stream>>>(img_idx, img_vals, vemb,     h1buf, 81920, 1);
    k_spmm_l2<<<2048, 256, 0, stream>>>(txt_idx, txt_vals, temb,     h2buf, 81920, 1);

    // ---- propagates ----
    auto propagate = [&](const float* item_part, bool filtered, const float* extra, int pcol){
        k_init<<<2560, 256, 0, stream>>>(user_emb, item_part, ego_a, accm);
        float* cur = ego_a; float* nxt = ego_b;
        if (!filtered) k_dinvcnt<<<160, 256, 0, stream>>>(ptr, dinv);
        for (int l = 0; l < 2; l++){
            if (filtered){
                k_mask<<<8192, 256, 0, stream>>>(ptr, csrc, ceid, cur, mbuf, dinv);
                k_itemdeg<<<2048, 256, 0, stream>>>(ptr, ceid, mbuf, dinv);
            }
            k_gemm64<<<10240, 256, 0, stream>>>(cur, convW + l*64*64, dinv, gbuf);
            if (filtered)
                k_agg<true><<<10240, 256, 0, stream>>>(ptr, csrc, ceid, mbuf, gbuf, dinv, convb + l*64, nxt, accm);
            else
                k_agg<false><<<10240, 256, 0, stream>>>(ptr, csrc, ceid, nullptr, gbuf, dinv, convb + l*64, nxt, accm);
            float* t = cur; cur = nxt; nxt = t;
        }
        k_final<<<2560, 256, 0, stream>>>(accm, extra, out, pcol);
    };

    propagate(vemb,     true,  h1buf, 1);   // u_v / i_v
    propagate(temb,     true,  h2buf, 2);   // u_t / i_t
    propagate(item_emb, false, hbuf,  0);   // u_g / i_g
}

// Round 3
// 1484.715 us; speedup vs baseline: 1.2582x; 1.2582x over previous
//
#include <hip/hip_runtime.h>
#include <cmath>

#define NUs 32768
#define NIs 8192
#define NNs 40960   // NUs + NIs
#define NEs 2000000

__device__ __forceinline__ float4 ld4(const float* p){ return *reinterpret_cast<const float4*>(p); }
__device__ __forceinline__ void st4(float* p, float4 v){ *reinterpret_cast<float4*>(p) = v; }

// ---------------- CSR build ----------------
__global__ void k_hist(const int* __restrict__ eu, const int* __restrict__ ev, int* __restrict__ cnt){
    int e = blockIdx.x*blockDim.x + threadIdx.x;
    if (e < NEs){ atomicAdd(&cnt[eu[e]], 1); atomicAdd(&cnt[ev[e]], 1); }
}

__global__ void k_bsum(const int* __restrict__ cnt, int* __restrict__ bsum){
    __shared__ int s[256];
    int i = blockIdx.x*256 + threadIdx.x;
    s[threadIdx.x] = cnt[i];
    __syncthreads();
    for (int off=128; off>0; off>>=1){
        if (threadIdx.x < off) s[threadIdx.x] += s[threadIdx.x+off];
        __syncthreads();
    }
    if (threadIdx.x == 0) bsum[blockIdx.x] = s[0];
}

__global__ void k_bscan(const int* __restrict__ bsum, int* __restrict__ boff){
    __shared__ int s[256];
    int t = threadIdx.x;
    int v0 = (t < 160) ? bsum[t] : 0;
    s[t] = v0;
    __syncthreads();
    for (int off=1; off<256; off<<=1){
        int v = (t >= off) ? s[t-off] : 0;
        __syncthreads();
        s[t] += v;
        __syncthreads();
    }
    if (t < 160) boff[t] = s[t] - v0;   // exclusive block offsets
}

__global__ void k_ptr(const int* __restrict__ cnt, const int* __restrict__ boff,
                      int* __restrict__ ptr, int* __restrict__ fill){
    __shared__ int s[256];
    int t = threadIdx.x; int i = blockIdx.x*256 + t;
    int c = cnt[i];
    s[t] = c; __syncthreads();
    for (int off=1; off<256; off<<=1){
        int v = (t >= off) ? s[t-off] : 0;
        __syncthreads();
        s[t] += v;
        __syncthreads();
    }
    int excl = boff[blockIdx.x] + s[t] - c;
    ptr[i] = excl; fill[i] = excl;
    if (i == NNs-1) ptr[NNs] = excl + c;
}

// user-side slot (pos in [0,NEs)): item-local id (4B)
// item-side slot (pos in [NEs,2*NEs)): ((ulonglong)upos << 32) | user  (8B), stored at pos-NEs
__global__ void k_scatter(const int* __restrict__ eu, const int* __restrict__ ev,
                          int* __restrict__ fill, int* __restrict__ csr_u,
                          unsigned long long* __restrict__ csr_i){
    int e = blockIdx.x*blockDim.x + threadIdx.x;
    if (e >= NEs) return;
    int u = eu[e], v = ev[e];
    int upos = atomicAdd(&fill[u], 1);
    csr_u[upos] = v - NUs;
    int ipos = atomicAdd(&fill[v], 1);
    csr_i[ipos - NEs] = ((unsigned long long)(unsigned)upos << 32) | (unsigned)u;
}

// ---------------- feature GEMMs: out(NI x 64) = A(NI x K) @ W(64 x K)^T + bias ----------------
template<int K>
__global__ __launch_bounds__(256) void k_featgemm(const float* __restrict__ A, const float* __restrict__ W,
                                                  const float* __restrict__ bias, float* __restrict__ out){
    __shared__ float As[32][65];
    __shared__ float Ws[64][65];
    int tid = threadIdx.x;
    int tx = tid & 15, ty = tid >> 4;
    int r0 = blockIdx.x * 32;
    float acc[2][4] = {};
    for (int kt = 0; kt < K; kt += 64){
        #pragma unroll
        for (int l = 0; l < 8; l++){
            int i = l*256 + tid;
            int rr = i >> 6, kk = i & 63;
            As[rr][kk] = A[(size_t)(r0+rr)*K + kt + kk];
        }
        #pragma unroll
        for (int l = 0; l < 16; l++){
            int i = l*256 + tid;
            int rr = i >> 6, kk = i & 63;
            Ws[rr][kk] = W[(size_t)rr*K + kt + kk];
        }
        __syncthreads();
        #pragma unroll 8
        for (int kk = 0; kk < 64; kk++){
            float a[2], b[4];
            #pragma unroll
            for (int i = 0; i < 2; i++) a[i] = As[ty*2+i][kk];
            #pragma unroll
            for (int j = 0; j < 4; j++) b[j] = Ws[tx*4+j][kk];
            #pragma unroll
            for (int i = 0; i < 2; i++)
                #pragma unroll
                for (int j = 0; j < 4; j++)
                    acc[i][j] += a[i]*b[j];
        }
        __syncthreads();
    }
    #pragma unroll
    for (int i = 0; i < 2; i++)
        #pragma unroll
        for (int j = 0; j < 4; j++)
            out[(size_t)(r0+ty*2+i)*64 + tx*4+j] = acc[i][j] + bias[tx*4+j];
}

// ---------------- KNN SpMM + l2norm (rows are repeat(arange, 10)) ----------------
__global__ __launch_bounds__(256) void k_spmm_l2(const int* __restrict__ idx, const float* __restrict__ vals,
                                                 const float* __restrict__ src, float* __restrict__ out,
                                                 int stride, int parts){
    int wave = (blockIdx.x*blockDim.x + threadIdx.x) >> 6;
    if (wave >= NIs) return;
    int lane = threadIdx.x & 63;
    const int* cols = idx + stride;
    float acc = 0.f;
    for (int part = 0; part < parts; part++){
        int base = part*81920 + wave*10;
        #pragma unroll
        for (int j = 0; j < 10; j++){
            int e = base + j;
            acc += vals[e] * src[(size_t)cols[e]*64 + lane];
        }
    }
    float ss = acc*acc;
    #pragma unroll
    for (int mset = 1; mset < 64; mset <<= 1) ss += __shfl_xor(ss, mset, 64);
    float nrm = fmaxf(sqrtf(ss), 1e-12f);
    out[(size_t)wave*64 + lane] = acc / nrm;
}

// ---------------- propagate init: ego = accm = concat(user_emb, item_part) ----------------
__global__ __launch_bounds__(256) void k_init(const float* __restrict__ ue, const float* __restrict__ it,
                                              float* __restrict__ ego, float* __restrict__ accm){
    int i = blockIdx.x*blockDim.x + threadIdx.x;
    if (i >= NNs*16) return;
    int n = i >> 4, c = i & 15;
    float4 v = (n < NUs) ? ld4(ue + (size_t)n*64 + c*4)
                         : ld4(it + (size_t)(n-NUs)*64 + c*4);
    st4(ego  + (size_t)n*64 + c*4, v);
    st4(accm + (size_t)n*64 + c*4, v);
}

// ---------------- mask pass (user side): bit[upos] = (ego[u].ego[i] >= 0), user dinv ----------------
__global__ __launch_bounds__(256) void k_mask(const int* __restrict__ ptr, const int* __restrict__ csr_u,
                                              const float* __restrict__ ego,
                                              unsigned int* __restrict__ mbits, float* __restrict__ dinv){
    int wave = (blockIdx.x*blockDim.x + threadIdx.x) >> 6;
    if (wave >= NUs) return;
    int lane = threadIdx.x & 63;
    int q = lane >> 4, r = lane & 15;
    float4 eu4 = ld4(ego + (size_t)wave*64 + r*4);
    int jb = ptr[wave], je = ptr[wave+1];
    float msum = 0.f;
    int j = jb + q;
    for (; j + 4 < je; j += 8){
        int s0 = NUs + csr_u[j];
        int s1 = NUs + csr_u[j+4];
        float4 v0 = ld4(ego + (size_t)s0*64 + r*4);
        float4 v1 = ld4(ego + (size_t)s1*64 + r*4);
        float d0 = eu4.x*v0.x + eu4.y*v0.y + eu4.z*v0.z + eu4.w*v0.w;
        float d1 = eu4.x*v1.x + eu4.y*v1.y + eu4.z*v1.z + eu4.w*v1.w;
        d0 += __shfl_xor(d0, 1, 64); d1 += __shfl_xor(d1, 1, 64);
        d0 += __shfl_xor(d0, 2, 64); d1 += __shfl_xor(d1, 2, 64);
        d0 += __shfl_xor(d0, 4, 64); d1 += __shfl_xor(d1, 4, 64);
        d0 += __shfl_xor(d0, 8, 64); d1 += __shfl_xor(d1, 8, 64);
        if (r == 0){
            if (d0 >= 0.f){ atomicOr(&mbits[j>>5], 1u << (j & 31)); msum += 1.f; }
            int j1 = j + 4;
            if (d1 >= 0.f){ atomicOr(&mbits[j1>>5], 1u << (j1 & 31)); msum += 1.f; }
        }
    }
    for (; j < je; j += 4){
        int s0 = NUs + csr_u[j];
        float4 v0 = ld4(ego + (size_t)s0*64 + r*4);
        float d0 = eu4.x*v0.x + eu4.y*v0.y + eu4.z*v0.z + eu4.w*v0.w;
        d0 += __shfl_xor(d0, 1, 64);
        d0 += __shfl_xor(d0, 2, 64);
        d0 += __shfl_xor(d0, 4, 64);
        d0 += __shfl_xor(d0, 8, 64);
        if (r == 0 && d0 >= 0.f){ atomicOr(&mbits[j>>5], 1u << (j & 31)); msum += 1.f; }
    }
    msum += __shfl_xor(msum, 16, 64);
    msum += __shfl_xor(msum, 32, 64);
    if (lane == 0) dinv[wave] = rsqrtf(msum + 1.0f);
}

// ---------------- item-side masked degree ----------------
__global__ __launch_bounds__(256) void k_itemdeg(const int* __restrict__ ptr, const unsigned long long* __restrict__ csr_i,
                                                 const unsigned int* __restrict__ mbits, float* __restrict__ dinv){
    int wave = (blockIdx.x*blockDim.x + threadIdx.x) >> 6;
    if (wave >= NIs) return;
    int n = NUs + wave;
    int lane = threadIdx.x & 63;
    int jb = ptr[n], je = ptr[n+1];
    float s = 0.f;
    for (int j = jb + lane; j < je; j += 64){
        unsigned int upos = (unsigned int)(csr_i[j - NEs] >> 32);
        s += (float)((mbits[upos >> 5] >> (upos & 31)) & 1u);
    }
    #pragma unroll
    for (int k = 1; k < 64; k <<= 1) s += __shfl_xor(s, k, 64);
    if (lane == 0) dinv[n] = rsqrtf(s + 1.0f);
}

// ---------------- unmasked dinv from counts ----------------
__global__ void k_dinvcnt(const int* __restrict__ ptr, float* __restrict__ dinv){
    int n = blockIdx.x*blockDim.x + threadIdx.x;
    if (n < NNs) dinv[n] = rsqrtf((float)(ptr[n+1]-ptr[n]) + 1.0f);
}

// ---------------- per-layer 64x64 GEMM with dinv premultiply: g = (ego @ W^T) * dinv[row] ----------------
__global__ __launch_bounds__(256) void k_gemm64(const float* __restrict__ ego, const float* __restrict__ W,
                                                const float* __restrict__ dinv, float* __restrict__ g){
    __shared__ float WT[64*65];
    int tid = threadIdx.x;
    #pragma unroll
    for (int l = 0; l < 16; l++){
        int i = l*256 + tid;
        int d = i >> 6, k = i & 63;
        WT[k*65 + d] = W[i];
    }
    __syncthreads();
    int lane = tid & 63; int wv = tid >> 6;
    int row = blockIdx.x*4 + wv;
    const float* er = ego + (size_t)row*64;
    float acc = 0.f;
    #pragma unroll 8
    for (int k = 0; k < 64; k++) acc += er[k] * WT[k*65 + lane];
    g[(size_t)row*64 + lane] = acc * dinv[row];
}

// ---------------- aggregation: ego' = dinv_dst*(sum_{src,m=1} g[src] + g[dst]) + b; accm += ego' ----------------
template<bool MASKED>
__global__ __launch_bounds__(256) void k_agg(const int* __restrict__ ptr, const int* __restrict__ csr_u,
                                             const unsigned long long* __restrict__ csr_i,
                                             const unsigned int* __restrict__ mbits,
                                             const float* __restrict__ g, const float* __restrict__ dinv,
                                             const float* __restrict__ bias,
                                             float* __restrict__ egon, float* __restrict__ accm){
    int wave = (blockIdx.x*blockDim.x + threadIdx.x) >> 6;
    if (wave >= NNs) return;
    int lane = threadIdx.x & 63;
    int q = lane >> 4, r = lane & 15;
    int jb = ptr[wave], je = ptr[wave+1];
    float4 acc = {0.f,0.f,0.f,0.f};

    if (wave < NUs){
        // dst = user; srcs are items (g window 2MB, L2-resident); mask bit = own position j
        int j = jb + q;
        for (; j + 12 < je; j += 16){
            int s0 = csr_u[j],   s1 = csr_u[j+4], s2 = csr_u[j+8], s3 = csr_u[j+12];
            bool w0 = true, w1 = true, w2 = true, w3 = true;
            if (MASKED){
                w0 = (mbits[j>>5]      >> (j&31))      & 1u;
                w1 = (mbits[(j+4)>>5]  >> ((j+4)&31))  & 1u;
                w2 = (mbits[(j+8)>>5]  >> ((j+8)&31))  & 1u;
                w3 = (mbits[(j+12)>>5] >> ((j+12)&31)) & 1u;
            }
            if (w0){ float4 v = ld4(g + (size_t)(NUs+s0)*64 + r*4); acc.x+=v.x; acc.y+=v.y; acc.z+=v.z; acc.w+=v.w; }
            if (w1){ float4 v = ld4(g + (size_t)(NUs+s1)*64 + r*4); acc.x+=v.x; acc.y+=v.y; acc.z+=v.z; acc.w+=v.w; }
            if (w2){ float4 v = ld4(g + (size_t)(NUs+s2)*64 + r*4); acc.x+=v.x; acc.y+=v.y; acc.z+=v.z; acc.w+=v.w; }
            if (w3){ float4 v = ld4(g + (size_t)(NUs+s3)*64 + r*4); acc.x+=v.x; acc.y+=v.y; acc.z+=v.z; acc.w+=v.w; }
        }
        for (; j < je; j += 4){
            bool w0 = true;
            if (MASKED) w0 = (mbits[j>>5] >> (j&31)) & 1u;
            if (w0){ float4 v = ld4(g + (size_t)(NUs+csr_u[j])*64 + r*4); acc.x+=v.x; acc.y+=v.y; acc.z+=v.z; acc.w+=v.w; }
        }
    } else {
        // dst = item; srcs are users; mask bit at upos from packed entry
        const unsigned long long* ci = csr_i - NEs;
        int j = jb + q;
        for (; j + 12 < je; j += 16){
            unsigned long long p0 = ci[j], p1 = ci[j+4], p2 = ci[j+8], p3 = ci[j+12];
            bool w0 = true, w1 = true, w2 = true, w3 = true;
            if (MASKED){
                unsigned int a0 = (unsigned int)(p0>>32), a1 = (unsigned int)(p1>>32);
                unsigned int a2 = (unsigned int)(p2>>32), a3 = (unsigned int)(p3>>32);
                w0 = (mbits[a0>>5] >> (a0&31)) & 1u;
                w1 = (mbits[a1>>5] >> (a1&31)) & 1u;
                w2 = (mbits[a2>>5] >> (a2&31)) & 1u;
                w3 = (mbits[a3>>5] >> (a3&31)) & 1u;
            }
            if (w0){ float4 v = ld4(g + (size_t)(unsigned int)p0*64 + r*4); acc.x+=v.x; acc.y+=v.y; acc.z+=v.z; acc.w+=v.w; }
            if (w1){ float4 v = ld4(g + (size_t)(unsigned int)p1*64 + r*4); acc.x+=v.x; acc.y+=v.y; acc.z+=v.z; acc.w+=v.w; }
            if (w2){ float4 v = ld4(g + (size_t)(unsigned int)p2*64 + r*4); acc.x+=v.x; acc.y+=v.y; acc.z+=v.z; acc.w+=v.w; }
            if (w3){ float4 v = ld4(g + (size_t)(unsigned int)p3*64 + r*4); acc.x+=v.x; acc.y+=v.y; acc.z+=v.z; acc.w+=v.w; }
        }
        for (; j < je; j += 4){
            unsigned long long p0 = ci[j];
            bool w0 = true;
            if (MASKED){
                unsigned int a0 = (unsigned int)(p0>>32);
                w0 = (mbits[a0>>5] >> (a0&31)) & 1u;
            }
            if (w0){ float4 v = ld4(g + (size_t)(unsigned int)p0*64 + r*4); acc.x+=v.x; acc.y+=v.y; acc.z+=v.z; acc.w+=v.w; }
        }
    }

    // reduce across the 4 q-groups
    acc.x += __shfl_xor(acc.x, 16, 64); acc.y += __shfl_xor(acc.y, 16, 64);
    acc.z += __shfl_xor(acc.z, 16, 64); acc.w += __shfl_xor(acc.w, 16, 64);
    acc.x += __shfl_xor(acc.x, 32, 64); acc.y += __shfl_xor(acc.y, 32, 64);
    acc.z += __shfl_xor(acc.z, 32, 64); acc.w += __shfl_xor(acc.w, 32, 64);
    if (q == 0){
        float dn = dinv[wave];
        float4 gs = ld4(g + (size_t)wave*64 + r*4);
        float4 o;
        o.x = dn*(acc.x + gs.x) + bias[r*4+0];
        o.y = dn*(acc.y + gs.y) + bias[r*4+1];
        o.z = dn*(acc.z + gs.z) + bias[r*4+2];
        o.w = dn*(acc.w + gs.w) + bias[r*4+3];
        st4(egon + (size_t)wave*64 + r*4, o);
        float4 am = ld4(accm + (size_t)wave*64 + r*4);
        am.x += o.x; am.y += o.y; am.z += o.z; am.w += o.w;
        st4(accm + (size_t)wave*64 + r*4, am);
    }
}

// ---------------- final: out[:, p*64:(p+1)*64] = accm/3 (+ extra for item rows) ----------------
__global__ __launch_bounds__(256) void k_final(const float* __restrict__ accm, const float* __restrict__ extra,
                                               float* __restrict__ out, int p){
    int i = blockIdx.x*blockDim.x + threadIdx.x;
    if (i >= NNs*16) return;
    int n = i >> 4, c = i & 15;
    float4 v = ld4(accm + (size_t)n*64 + c*4);
    const float third = 1.0f/3.0f;
    v.x *= third; v.y *= third; v.z *= third; v.w *= third;
    if (n >= NUs){
        float4 e = ld4(extra + (size_t)(n-NUs)*64 + c*4);
        v.x += e.x; v.y += e.y; v.z += e.z; v.w += e.w;
    }
    st4(out + (size_t)n*192 + p*64 + c*4, v);
}

extern "C" void kernel_launch(void* const* d_in, const int* in_sizes, int n_in,
                              void* d_out, int out_size, void* d_ws, size_t ws_size,
                              hipStream_t stream){
    const float* user_emb = (const float*)d_in[0];
    const float* item_emb = (const float*)d_in[1];
    const float* v_feat   = (const float*)d_in[2];
    const float* t_feat   = (const float*)d_in[3];
    const float* Wi       = (const float*)d_in[4];
    const float* bi       = (const float*)d_in[5];
    const float* Wt       = (const float*)d_in[6];
    const float* bt       = (const float*)d_in[7];
    const float* convW    = (const float*)d_in[8];
    const float* convb    = (const float*)d_in[9];
    const int*   edge     = (const int*)d_in[10];
    const int*   img_idx  = (const int*)d_in[11];
    const float* img_vals = (const float*)d_in[12];
    const int*   txt_idx  = (const int*)d_in[13];
    const float* txt_vals = (const float*)d_in[14];
    const int*   mm_idx   = (const int*)d_in[15];
    const float* mm_vals  = (const float*)d_in[16];
    float* out = (float*)d_out;

    const int* eu = edge;
    const int* ev = edge + NEs;

    char* wsb = (char*)d_ws;
    size_t off = 0;
    auto alloc = [&](size_t b)->char*{ char* p = wsb + off; off = (off + b + 255) & ~(size_t)255; return p; };
    int*   cnt   = (int*)  alloc((size_t)NNs*4);
    int*   fill  = (int*)  alloc((size_t)NNs*4);
    int*   ptr   = (int*)  alloc((size_t)(NNs+1)*4);
    int*   bsum  = (int*)  alloc(160*4);
    int*   boff  = (int*)  alloc(160*4);
    int*   csr_u = (int*)  alloc((size_t)NEs*4);                    // 8 MB
    unsigned long long* csr_i = (unsigned long long*)alloc((size_t)NEs*8); // 16 MB
    unsigned int* mbits = (unsigned int*)alloc((size_t)((NEs+31)/32)*4);   // 250 KB
    float* dinv  = (float*)alloc((size_t)NNs*4);
    float* ego_a = (float*)alloc((size_t)NNs*64*4);
    float* ego_b = (float*)alloc((size_t)NNs*64*4);
    float* gbuf  = (float*)alloc((size_t)NNs*64*4);
    float* accm  = (float*)alloc((size_t)NNs*64*4);
    float* vemb  = (float*)alloc((size_t)NIs*64*4);
    float* temb  = (float*)alloc((size_t)NIs*64*4);
    float* hbuf  = (float*)alloc((size_t)NIs*64*4);
    float* h1buf = (float*)alloc((size_t)NIs*64*4);
    float* h2buf = (float*)alloc((size_t)NIs*64*4);

    // ---- CSR build ----
    hipMemsetAsync(cnt, 0, (size_t)NNs*4, stream);
    int eblk = (NEs + 255)/256;
    k_hist<<<eblk, 256, 0, stream>>>(eu, ev, cnt);
    k_bsum<<<160, 256, 0, stream>>>(cnt, bsum);
    k_bscan<<<1, 256, 0, stream>>>(bsum, boff);
    k_ptr<<<160, 256, 0, stream>>>(cnt, boff, ptr, fill);
    k_scatter<<<eblk, 256, 0, stream>>>(eu, ev, fill, csr_u, csr_i);

    // ---- feature embeddings ----
    k_featgemm<1024><<<256, 256, 0, stream>>>(v_feat, Wi, bi, vemb);
    k_featgemm<384> <<<256, 256, 0, stream>>>(t_feat, Wt, bt, temb);

    // ---- KNN spmm + l2norm ----
    k_spmm_l2<<<2048, 256, 0, stream>>>(mm_idx,  mm_vals,  item_emb, hbuf,  163840, 2);
    k_spmm_l2<<<2048, 256, 0, stream>>>(img_idx, img_vals, vemb,     h1buf, 81920, 1);
    k_spmm_l2<<<2048, 256, 0, stream>>>(txt_idx, txt_vals, temb,     h2buf, 81920, 1);

    // ---- propagates ----
    auto propagate = [&](const float* item_part, bool filtered, const float* extra, int pcol){
        k_init<<<2560, 256, 0, stream>>>(user_emb, item_part, ego_a, accm);
        float* cur = ego_a; float* nxt = ego_b;
        if (!filtered) k_dinvcnt<<<160, 256, 0, stream>>>(ptr, dinv);
        for (int l = 0; l < 2; l++){
            if (filtered){
                hipMemsetAsync(mbits, 0, (size_t)((NEs+31)/32)*4, stream);
                k_mask<<<8192, 256, 0, stream>>>(ptr, csr_u, cur, mbits, dinv);
                k_itemdeg<<<2048, 256, 0, stream>>>(ptr, csr_i, mbits, dinv);
            }
            k_gemm64<<<10240, 256, 0, stream>>>(cur, convW + l*64*64, dinv, gbuf);
            if (filtered)
                k_agg<true><<<10240, 256, 0, stream>>>(ptr, csr_u, csr_i, mbits, gbuf, dinv, convb + l*64, nxt, accm);
            else
                k_agg<false><<<10240, 256, 0, stream>>>(ptr, csr_u, csr_i, nullptr, gbuf, dinv, convb + l*64, nxt, accm);
            float* t = cur; cur = nxt; nxt = t;
        }
        k_final<<<2560, 256, 0, stream>>>(accm, extra, out, pcol);
    };

    propagate(vemb,     true,  h1buf, 1);   // u_v / i_v
    propagate(temb,     true,  h2buf, 2);   // u_t / i_t
    propagate(item_emb, false, hbuf,  0);   // u_g / i_g
}